// Round 8
// baseline (327.667 us; speedup 1.0000x reference)
//
#include <hip/hip_runtime.h>

#define Bsz   1024
#define Tlen  512
#define VOC   8
#define EDIM  32
#define HDIM  64
#define G4    256
#define SEQB  4                  // sequences per block, mapped to A-rows {0,4,8,12}
#define NT    512                // 8 waves: 0-3 = layer0 (producers), 4-7 = layer1 (consumers)
#define NBLK  (Bsz / SEQB)       // 256 blocks -> all 256 CUs

typedef _Float16 f16x8 __attribute__((ext_vector_type(8)));
typedef float    f32x4 __attribute__((ext_vector_type(4)));

__device__ __forceinline__ float ex2(float x) {
#if __has_builtin(__builtin_amdgcn_exp2f)
    return __builtin_amdgcn_exp2f(x);
#else
    return exp2f(x);
#endif
}
__device__ __forceinline__ float rcp_(float x) {
#if __has_builtin(__builtin_amdgcn_rcpf)
    return __builtin_amdgcn_rcpf(x);
#else
    return 1.0f / x;
#endif
}

// paired-rcp LSTM cell update: 5 exp2 + 3 rcp (+clamps) per (seq,col)  [identical to R7]
__device__ __forceinline__ void cell_upd(float ai, float af, float ag, float ao,
                                         float& c, float& h) {
    const float K1 = 1.4426950408889634f;
    float ei = ex2(fminf(-K1 * ai, 60.0f));
    float ef = ex2(fminf(-K1 * af, 60.0f));
    float eg = ex2(fminf(-2.0f * K1 * ag, 60.0f));
    float eo = ex2(fminf(-K1 * ao, 60.0f));
    float di = 1.0f + ei, df = 1.0f + ef, dg = 1.0f + eg, dn = 1.0f + eo;
    float r1 = rcp_(di * df);
    float si = df * r1;                                  // sigmoid(ai)
    float sf = di * r1;                                  // sigmoid(af)
    float r2 = rcp_(dg * dn);
    float tg = __builtin_fmaf(2.0f * dn, r2, -1.0f);     // tanh(ag)
    float so = dg * r2;                                  // sigmoid(ao)
    c = sf * c + si * tg;
    float ec = ex2(fminf(-2.0f * K1 * c, 60.0f));
    h = so * __builtin_fmaf(2.0f, rcp_(1.0f + ec), -1.0f);
}

// ws: [0 .. 2048) packed layer0 gate table: float4{i,f,g,o}[voc][hcol]
//     [2048 .. 2304) bih1+bhh1 (gate index 64q+c)
__global__ void precompute_kernel(const float* __restrict__ emb,
                                  const float* __restrict__ Wih0,
                                  const float* __restrict__ bih0,
                                  const float* __restrict__ bhh0,
                                  const float* __restrict__ bih1,
                                  const float* __restrict__ bhh1,
                                  float* __restrict__ ws) {
    int g = threadIdx.x;
    int v = blockIdx.x;
    if (v < VOC) {
        float acc = bih0[g] + bhh0[g];
        #pragma unroll
        for (int e = 0; e < EDIM; ++e)
            acc += Wih0[g * EDIM + e] * emb[v * EDIM + e];
        const int q = g >> 6, c = g & 63;
        ws[(v * 64 + c) * 4 + q] = acc;
    } else {
        ws[VOC * G4 + g] = bih1[g] + bhh1[g];
    }
}

// h LDS layout = A-fragment order for mfma_f32_16x16x32_f16 (validated R4/R7):
__device__ __forceinline__ f16x8 read_h_frag(const _Float16* hb, int kc, int l) {
    int off = kc * 512 + ((l * 8) ^ ((l & 3) << 7));
    return *(const f16x8*)(hb + off);
}
__device__ __forceinline__ void write_h(_Float16* hb, int r, int c, float v) {
    int off = (c >> 5) * 512 +
              (((((c & 31) >> 3) * 128) + r * 8 + (c & 7)) ^ ((r & 3) << 7));
    hb[off] = (_Float16)v;
}

// wave-level producer/consumer sync via monotonic LDS counters
__device__ __forceinline__ void sync_wait(volatile int* c, int need0, int need1) {
    for (;;) {
        int m0 = min(min(c[0], c[1]), min(c[2], c[3]));
        int m1 = min(min(c[4], c[5]), min(c[6], c[7]));
        if (m0 >= need0 && m1 >= need1) break;
    }
    __builtin_amdgcn_sched_barrier(0);          // rule #18: keep later ds_reads below the poll
    asm volatile("" ::: "memory");
}
__device__ __forceinline__ void publish(volatile int* c, int idx, int v, int lane) {
    asm volatile("s_waitcnt lgkmcnt(0)" ::: "memory");   // data writes landed before flag
    if (lane == 0) c[idx] = v;
}

__global__ __launch_bounds__(NT)
void lstm_kernel(const int*   __restrict__ x,
                 const float* __restrict__ Whh0,
                 const float* __restrict__ Wih1,
                 const float* __restrict__ Whh1,
                 const float* __restrict__ Wfc,
                 const float* __restrict__ bfc,
                 const float* __restrict__ ws,
                 float* __restrict__ out) {
    __shared__ float4    stbl4[VOC * 64];        // 8 KB packed gate table
    __shared__ int       sxl[SEQB * Tlen];       // 8 KB tokens [seq][t]
    __shared__ _Float16  h0r[4][1024];           // 8 KB h0 ring, slot t&3 = h0(t)
    __shared__ _Float16  h1r[4][1024];           // 8 KB h1 ring, slot t&3 = h1(t)
    __shared__ float     sh1f[SEQB][HDIM + 1];   // final h1, fp32
    __shared__ int       scnt[8];                // [0..3]=L0 wave steps, [4..7]=L1

    const int tid  = threadIdx.x;
    const int b0   = blockIdx.x * SEQB;
    const int l    = tid & 63;
    const int wid  = tid >> 6;
    const bool isL1 = (wid >= 4);
    const int w    = wid & 3;                    // col block: cols [16w,16w+16)
    const int l15  = l & 15;
    const int kb   = (l >> 4) * 8;
    const int cq0  = 16 * w + l15;               // this lane's hidden col
    const int s    = l >> 4;                     // this lane's assigned seq (0..3) -> A-row 4s
    const int r4   = 4 * s;                      // seq's A/D row
    volatile int* vcnt = scnt;

    for (int i = tid; i < VOC * 64; i += NT)
        stbl4[i] = ((const float4*)ws)[i];
    for (int i = tid; i < SEQB * Tlen; i += NT)
        sxl[i] = x[b0 * Tlen + i];
    for (int i = tid; i < 4 * 1024; i += NT) {
        h0r[0][i] = (_Float16)0.0f;              // flat zero of both rings
        h1r[0][i] = (_Float16)0.0f;
    }
    if (tid < 8) scnt[tid] = 0;

    // loop-invariant weight B-fragments: lane holds W[col=64q+16w+l15][kc*32+kb+i]
    f16x8 wA0[4], wA1[4], wI0[4], wI1[4], wH0[4], wH1[4];
    float b1s[4];
    if (!isL1) {
        #pragma unroll
        for (int q = 0; q < 4; ++q) {
            const int cq = 64 * q + cq0;
            const float* p0 = Whh0 + cq * HDIM + kb;
            const float* p1 = Whh0 + cq * HDIM + 32 + kb;
            #pragma unroll
            for (int i = 0; i < 8; ++i) { wA0[q][i] = (_Float16)p0[i]; wA1[q][i] = (_Float16)p1[i]; }
        }
    } else {
        #pragma unroll
        for (int q = 0; q < 4; ++q) {
            const int cq = 64 * q + cq0;
            b1s[q] = ws[VOC * G4 + cq];
            const float* pi0 = Wih1 + cq * HDIM + kb;
            const float* pi1 = Wih1 + cq * HDIM + 32 + kb;
            const float* ph0 = Whh1 + cq * HDIM + kb;
            const float* ph1 = Whh1 + cq * HDIM + 32 + kb;
            #pragma unroll
            for (int i = 0; i < 8; ++i) {
                wI0[q][i] = (_Float16)pi0[i]; wI1[q][i] = (_Float16)pi1[i];
                wH0[q][i] = (_Float16)ph0[i]; wH1[q][i] = (_Float16)ph1[i];
            }
        }
    }

    float cst = 0.0f;            // cell state for (seq s, col cq0)
    __syncthreads();             // staging + counters visible to all waves

    if (!isL1) {
        // ---- layer0 producer: step t reads h0(t-1) [slot (t-1)&3], writes h0(t) [slot t&3]
        int tc = sxl[s * Tlen];
        #pragma unroll 1
        for (int t = 0; t < Tlen; ++t) {
            // all L0 waves done step t-1; L1 done step t-4 (ring slot t&3 free)
            sync_wait(vcnt, t, t - 3);
            const _Float16* h0b = h0r[(t - 1) & 3];
            f16x8 a0 = read_h_frag(h0b, 0, l);
            f16x8 a1 = read_h_frag(h0b, 1, l);
            f32x4 tq = *(const f32x4*)&stbl4[tc * 64 + cq0];   // C-init gather, early
            f32x4 acc0 = (f32x4)(0.0f), acc1 = (f32x4)(0.0f);
            f32x4 acc2 = (f32x4)(0.0f), acc3 = (f32x4)(0.0f);
            acc0 = __builtin_amdgcn_mfma_f32_16x16x32_f16(a0, wA0[0], acc0, 0, 0, 0);
            acc1 = __builtin_amdgcn_mfma_f32_16x16x32_f16(a0, wA0[1], acc1, 0, 0, 0);
            acc2 = __builtin_amdgcn_mfma_f32_16x16x32_f16(a0, wA0[2], acc2, 0, 0, 0);
            acc3 = __builtin_amdgcn_mfma_f32_16x16x32_f16(a0, wA0[3], acc3, 0, 0, 0);
            acc0 = __builtin_amdgcn_mfma_f32_16x16x32_f16(a1, wA1[0], acc0, 0, 0, 0);
            acc1 = __builtin_amdgcn_mfma_f32_16x16x32_f16(a1, wA1[1], acc1, 0, 0, 0);
            acc2 = __builtin_amdgcn_mfma_f32_16x16x32_f16(a1, wA1[2], acc2, 0, 0, 0);
            acc3 = __builtin_amdgcn_mfma_f32_16x16x32_f16(a1, wA1[3], acc3, 0, 0, 0);

            const int kn = (t + 1 < Tlen) ? (t + 1) : (Tlen - 1);
            const int tnext = sxl[s * Tlen + kn];

            float ai = acc0[0] + tq[0];
            float af = acc1[0] + tq[1];
            float ag = acc2[0] + tq[2];
            float ao = acc3[0] + tq[3];
            float hv;
            cell_upd(ai, af, ag, ao, cst, hv);
            write_h(h0r[t & 3], r4, cq0, hv);
            publish(vcnt, wid, t + 1, l);
            tc = tnext;
        }
    } else {
        // ---- layer1 consumer: step t reads h0(t) [slot t&3] + h1(t-1) [slot (t-1)&3]
        #pragma unroll 1
        for (int t = 0; t < Tlen; ++t) {
            sync_wait(vcnt, t + 1, t);
            const _Float16* h0b = h0r[t & 3];
            const _Float16* h1b = h1r[(t - 1) & 3];
            f16x8 a0  = read_h_frag(h0b, 0, l);
            f16x8 a1  = read_h_frag(h0b, 1, l);
            f16x8 b0f = read_h_frag(h1b, 0, l);
            f16x8 b1f = read_h_frag(h1b, 1, l);
            f32x4 acc0 = (f32x4)(0.0f), acc1 = (f32x4)(0.0f);
            f32x4 acc2 = (f32x4)(0.0f), acc3 = (f32x4)(0.0f);
            acc0 = __builtin_amdgcn_mfma_f32_16x16x32_f16(a0,  wI0[0], acc0, 0, 0, 0);
            acc1 = __builtin_amdgcn_mfma_f32_16x16x32_f16(a0,  wI0[1], acc1, 0, 0, 0);
            acc2 = __builtin_amdgcn_mfma_f32_16x16x32_f16(a0,  wI0[2], acc2, 0, 0, 0);
            acc3 = __builtin_amdgcn_mfma_f32_16x16x32_f16(a0,  wI0[3], acc3, 0, 0, 0);
            acc0 = __builtin_amdgcn_mfma_f32_16x16x32_f16(a1,  wI1[0], acc0, 0, 0, 0);
            acc1 = __builtin_amdgcn_mfma_f32_16x16x32_f16(a1,  wI1[1], acc1, 0, 0, 0);
            acc2 = __builtin_amdgcn_mfma_f32_16x16x32_f16(a1,  wI1[2], acc2, 0, 0, 0);
            acc3 = __builtin_amdgcn_mfma_f32_16x16x32_f16(a1,  wI1[3], acc3, 0, 0, 0);
            acc0 = __builtin_amdgcn_mfma_f32_16x16x32_f16(b0f, wH0[0], acc0, 0, 0, 0);
            acc1 = __builtin_amdgcn_mfma_f32_16x16x32_f16(b0f, wH0[1], acc1, 0, 0, 0);
            acc2 = __builtin_amdgcn_mfma_f32_16x16x32_f16(b0f, wH0[2], acc2, 0, 0, 0);
            acc3 = __builtin_amdgcn_mfma_f32_16x16x32_f16(b0f, wH0[3], acc3, 0, 0, 0);
            acc0 = __builtin_amdgcn_mfma_f32_16x16x32_f16(b1f, wH1[0], acc0, 0, 0, 0);
            acc1 = __builtin_amdgcn_mfma_f32_16x16x32_f16(b1f, wH1[1], acc1, 0, 0, 0);
            acc2 = __builtin_amdgcn_mfma_f32_16x16x32_f16(b1f, wH1[2], acc2, 0, 0, 0);
            acc3 = __builtin_amdgcn_mfma_f32_16x16x32_f16(b1f, wH1[3], acc3, 0, 0, 0);

            float ai = acc0[0] + b1s[0];
            float af = acc1[0] + b1s[1];
            float ag = acc2[0] + b1s[2];
            float ao = acc3[0] + b1s[3];
            float hv;
            cell_upd(ai, af, ag, ao, cst, hv);
            if (t == Tlen - 1) sh1f[s][cq0] = hv;        // final h1 in fp32
            else               write_h(h1r[t & 3], r4, cq0, hv);
            publish(vcnt, wid, t + 1, l);
        }
    }
    __syncthreads();

    // logits = h1(T-1) @ Wfc^T + bfc  (fp32)
    if (tid < SEQB * VOC) {
        const int seq = tid >> 3, v = tid & 7;
        float acc2 = bfc[v];
        #pragma unroll
        for (int j = 0; j < HDIM; ++j)
            acc2 += Wfc[v * HDIM + j] * sh1f[seq][j];
        out[(b0 + seq) * VOC + v] = acc2;
    }
}

extern "C" void kernel_launch(void* const* d_in, const int* in_sizes, int n_in,
                              void* d_out, int out_size, void* d_ws, size_t ws_size,
                              hipStream_t stream) {
    const int*   x    = (const int*)  d_in[0];
    const float* emb  = (const float*)d_in[1];
    const float* Wih0 = (const float*)d_in[2];
    const float* Whh0 = (const float*)d_in[3];
    const float* bih0 = (const float*)d_in[4];
    const float* bhh0 = (const float*)d_in[5];
    const float* Wih1 = (const float*)d_in[6];
    const float* Whh1 = (const float*)d_in[7];
    const float* bih1 = (const float*)d_in[8];
    const float* bhh1 = (const float*)d_in[9];
    const float* Wfc  = (const float*)d_in[10];
    const float* bfc  = (const float*)d_in[11];
    float* out = (float*)d_out;
    float* ws  = (float*)d_ws;

    hipLaunchKernelGGL(precompute_kernel, dim3(VOC + 1), dim3(G4), 0, stream,
                       emb, Wih0, bih0, bhh0, bih1, bhh1, ws);
    hipLaunchKernelGGL(lstm_kernel, dim3(NBLK), dim3(NT), 0, stream,
                       x, Whh0, Wih1, Whh1, Wfc, bfc, ws, out);
}